// Round 15
// baseline (111.067 us; speedup 1.0000x reference)
//
#include <hip/hip_runtime.h>

// GMELoss3D: fused 3D Sobel edge-magnitude MSE on [2,2,128,128,128] fp32 volumes.
// R17: HALVE THE WAIT-POINTS — 2 planes per s_waitcnt (9 waits/block vs 18).
//   - R16 post-mortem: 3KB body bought ~1%. Remaining stall: ~3400cy idle per
//     plane per wave at the wait point, with ~800cy of issue work. Ring depth
//     (R10), counted vmcnt (R15), body size (R16) all null — but EVERY round
//     had 18 wait-points/block. Surviving hypothesis: fixed ~1500-2000cy cost
//     per wait-point (return-rate pacing / wakeup), insensitive to nominal
//     cover. Direct test: halve the wait-point count, freeze everything else.
//   - Ring slot = 2 planes (24 dwordx2, 12KB/wave in flight per slot); ONE
//     vmcnt(24) per super-iteration covers both planes (slot issued 1 super-
//     iter = 2 plane-periods earlier); consume both; reissue 24.
//   - 10 super-iters = 20 planes: planes 18,19 are value-masked (fz) AND
//     emit-gated (j<=17, runtime compare) to avoid double-counting with the
//     next z-chunk — +11% wasted work buys an EVEN trip count so unroll 2
//     keeps i%2 / j%2 static (rule #20).
//   - VGPR est ~220 (pf 96 + K 56 + temps) — same <=256 / 2-waves-per-SIMD
//     tier as R12/R16. TRIPWIRE: WRITE_SIZE in MBs = spill -> revert to R16.
//   - PRE-COMMITTED: null => declare practical ceiling next round.
//   - Frozen from R16: full-row waves, dwordx2 asm loads, consume-time masks,
//     seam bperms, mod-2 K pipeline, v_sqrt_f32, 512 co-resident blocks,
//     no __syncthreads in z-loop, no launch_bounds waves clamp.
//
// Decomposition: s=[1,2,1], d=[-1,0,1], e=[1,1,1], y-first per plane:
//   C0=s_y d_x  C1=d_y s_x  C2=s_y s_x  C3=e_y d_x  C4=d_y e_x  C5=e_y s_x
//   C6=s_y e_x ; z-combines in emag_ss. Signs irrelevant (squared).

namespace {

typedef float v2f __attribute__((ext_vector_type(2)));

constexpr int ZDIM = 128, YDIM = 128, XDIM = 128;   // (H, W, D); D contiguous
constexpr int TX = 64, TY = 4, ZC = 16;
constexpr int NW = 10;                    // super-iterations (2 planes each)
constexpr int XW  = XDIM / 2;             // 64 float2 per row (lane i: x=2i,2i+1)
constexpr int YX2 = YDIM * XW;            // float2 per z-plane
constexpr size_t CS2 = (size_t)ZDIM * YX2;  // channel stride in float2
constexpr float INV_N = 1.0f / 4194304.0f;

__device__ __forceinline__ float bperm(int addr, float v) {
  return __int_as_float(__builtin_amdgcn_ds_bpermute(addr, __float_as_int(v)));
}

__device__ __forceinline__ v2f vfma(v2f a, v2f b, v2f c) {
  return __builtin_elementwise_fma(a, b, c);
}

__device__ __forceinline__ v2f vsplat(float x) { v2f r = {x, x}; return r; }

// packed (over 2 x-columns) sum-of-squares of the 9 gradients (+eps)
__device__ __forceinline__ v2f emag_ss(const v2f* __restrict__ Ca,
                                       const v2f* __restrict__ Cb,
                                       const v2f* __restrict__ Cc) {
  const v2f two = vsplat(2.0f);
  const v2f g1  = vfma(two, Cb[0], Ca[0] + Cc[0]);   // Sx
  const v2f g2  = vfma(two, Cb[1], Ca[1] + Cc[1]);   // Sy
  const v2f g3  = Cc[2] - Ca[2];                     // Sz
  const v2f Azx = vfma(two, Cb[3], Ca[3] + Cc[3]);   // s_z e_y d_x
  const v2f Azy = vfma(two, Cb[4], Ca[4] + Cc[4]);   // s_z d_y e_x
  const v2f Axz = Cc[5] - Ca[5];                     // d_z e_y s_x
  const v2f Axy = g2 - Cb[1];                        // e_z d_y s_x
  const v2f Ayx = g1 - Cb[0];                        // e_z s_y d_x
  const v2f Ayz = Cc[6] - Ca[6];                     // d_z s_y e_x
  const v2f g4 = Azx - Azy, g5 = Azx + Azy;          // Sd11, Sd12
  const v2f g6 = Axz - Axy, g7 = Axz + Axy;          // Sd21, Sd22
  const v2f g8 = Ayx - Ayz, g9 = Ayx + Ayz;          // Sd31, Sd32
  v2f s = vfma(g1, g1, vsplat(1e-12f));
  s = vfma(g2, g2, s); s = vfma(g3, g3, s);
  s = vfma(g4, g4, s); s = vfma(g5, g5, s);
  s = vfma(g6, g6, s); s = vfma(g7, g7, s);
  s = vfma(g8, g8, s); s = vfma(g9, g9, s);
  return s;
}

__global__ __launch_bounds__(256)       // natural allocation — NO waves clamp
void gme_loss_kernel(const float* __restrict__ y,
                     const float* __restrict__ yp,
                     float* __restrict__ out) {
  const int lane = threadIdx.x;          // lane i covers x = 2i, 2i+1 (full row)
  const int ty   = threadIdx.y;          // row within block (0..3); wave id
  const int tid  = ty * TX + lane;

  const int yy = blockIdx.x * TY + ty;   // global row 0..127 (wave-uniform)
  const int z0 = blockIdx.y * ZC;
  const int b  = blockIdx.z;

  const v2f* Y0 = (const v2f*)y  + (size_t)b * 2 * CS2;   // vol y, ch 0
  const v2f* Y1 = Y0 + CS2;                               // vol y, ch 1
  const v2f* P0 = (const v2f*)yp + (size_t)b * 2 * CS2;   // vol yp, ch 0
  const v2f* P1 = P0 + CS2;

  // y-clamped row bases (wave-uniform) + value masks for clamped rows
  const int yM = yy > 0 ? yy - 1 : 0;
  const int yP = yy < YDIM - 1 ? yy + 1 : YDIM - 1;
  const int oM8 = (yM * XW + lane) * 8;  // byte offsets for dwordx2
  const int oC8 = (yy * XW + lane) * 8;
  const int oP8 = (yP * XW + lane) * 8;
  const float mm = (yy > 0) ? 1.0f : 0.0f;
  const float mp = (yy < YDIM - 1) ? 1.0f : 0.0f;

  // seam exchange: prev lane's x1 (.y), next lane's x0 (.x); volume-edge zeros
  const int addrL = (lane > 0 ? lane - 1 : 0) << 2;
  const int addrR = (lane < TX - 1 ? lane + 1 : TX - 1) << 2;
  const float lz = (lane == 0) ? 0.0f : 1.0f;
  const float rz = (lane == TX - 1) ? 0.0f : 1.0f;

  // RAW ring, 2 SLOTS x 2 PLANES each (compiler-invisible asm loads).
  // slot layout: [0..11] plane A, [12..23] plane B; per plane:
  // [0]Y0m [1]Y1m [2]P0m [3]P1m [4]Y0c [5]Y1c [6]P0c [7]P1c [8]Y0p [9]Y1p [10]P0p [11]P1p
  v2f pf[2][24];
  v2f KY[2][7], KP[2][7];                // mod-2 combo pipeline (j-2, j-1)
  v2f accv = {0.0f, 0.0f};

  // 12 asm loads for ONE plane at base byte-offset zo (volatile: exact order)
  auto asmLoad1 = [&](v2f* d, int zo) {
    const int om = zo + oM8, oc = zo + oC8, op = zo + oP8;
    asm volatile("global_load_dwordx2 %0, %1, %2" : "=v"(d[0])  : "v"(om), "s"(Y0));
    asm volatile("global_load_dwordx2 %0, %1, %2" : "=v"(d[1])  : "v"(om), "s"(Y1));
    asm volatile("global_load_dwordx2 %0, %1, %2" : "=v"(d[2])  : "v"(om), "s"(P0));
    asm volatile("global_load_dwordx2 %0, %1, %2" : "=v"(d[3])  : "v"(om), "s"(P1));
    asm volatile("global_load_dwordx2 %0, %1, %2" : "=v"(d[4])  : "v"(oc), "s"(Y0));
    asm volatile("global_load_dwordx2 %0, %1, %2" : "=v"(d[5])  : "v"(oc), "s"(Y1));
    asm volatile("global_load_dwordx2 %0, %1, %2" : "=v"(d[6])  : "v"(oc), "s"(P0));
    asm volatile("global_load_dwordx2 %0, %1, %2" : "=v"(d[7])  : "v"(oc), "s"(P1));
    asm volatile("global_load_dwordx2 %0, %1, %2" : "=v"(d[8])  : "v"(op), "s"(Y0));
    asm volatile("global_load_dwordx2 %0, %1, %2" : "=v"(d[9])  : "v"(op), "s"(Y1));
    asm volatile("global_load_dwordx2 %0, %1, %2" : "=v"(d[10]) : "v"(op), "s"(P0));
    asm volatile("global_load_dwordx2 %0, %1, %2" : "=v"(d[11]) : "v"(op), "s"(P1));
  };

  // 24 loads: planes zcA (d[0..11]) and zcA+1 (d[12..23]), z-clamped
  auto asmLoad2 = [&](v2f* d, int zcA) {
    const int zA = zcA < 0 ? 0 : (zcA > ZDIM - 1 ? ZDIM - 1 : zcA);
    const int zB = zcA + 1 < 0 ? 0 : (zcA + 1 > ZDIM - 1 ? ZDIM - 1 : zcA + 1);
    asmLoad1(d, zA * (YX2 * 8));
    asmLoad1(d + 12, zB * (YX2 * 8));
  };

  // x-combine: from quantity q (v2f over x) build the 7 per-plane combos
  auto combos = [&](v2f ys, v2f yd, v2f ye, v2f* __restrict__ C) {
    const float ysl = bperm(addrL, ys.y) * lz, ysr = bperm(addrR, ys.x) * rz;
    const float ydl = bperm(addrL, yd.y) * lz, ydr = bperm(addrR, yd.x) * rz;
    const float yel = bperm(addrL, ye.y) * lz, yer = bperm(addrR, ye.x) * rz;
    const v2f ysL = {ysl, ys.x}, ysR = {ys.y, ysr};
    const v2f ydL = {ydl, yd.x}, ydR = {yd.y, ydr};
    const v2f yeL = {yel, ye.x}, yeR = {ye.y, yer};
    const v2f tS = ysL + ysR, tD = ydL + ydR, tE = yeL + yeR;
    C[0] = ysR - ysL;                           // s_y d_x
    C[2] = vfma(vsplat(2.0f), ys, tS);          // s_y s_x
    C[6] = tS + ys;                             // s_y e_x
    C[1] = vfma(vsplat(2.0f), yd, tD);          // d_y s_x
    C[4] = tD + yd;                             // d_y e_x
    C[3] = yeR - yeL;                           // e_y d_x
    C[5] = vfma(vsplat(2.0f), ye, tE);          // e_y s_x
  };

  // consume ONE plane's 12 raw v2f; jm = j%2 (compile-time 0/1 at call sites)
  auto consume = [&](const v2f* q, int jm, int j) {
    const int   zc = z0 - 1 + j;
    const float fz = ((unsigned)zc < (unsigned)ZDIM) ? 1.0f : 0.0f;
    const float eg = (j >= 2 && j <= ZC + 1) ? 1.0f : 0.0f;  // emit gate
    const v2f smY = (q[0] + q[1])   * vsplat(fz * mm);       // ch-sums, masked
    const v2f smP = (q[2] + q[3])   * vsplat(fz * mm);
    const v2f scY = (q[4] + q[5])   * vsplat(fz);
    const v2f scP = (q[6] + q[7])   * vsplat(fz);
    const v2f spY = (q[8] + q[9])   * vsplat(fz * mp);
    const v2f spP = (q[10] + q[11]) * vsplat(fz * mp);

    v2f Cy[7], Cp[7];
    {
      const v2f tt = smY + spY;
      combos(vfma(vsplat(2.0f), scY, tt), spY - smY, tt + scY, Cy);
    }
    {
      const v2f tt = smP + spP;
      combos(vfma(vsplat(2.0f), scP, tt), spP - smP, tt + scP, Cp);
    }

    // emit output plane z0+j-3 (gated by eg; K holds j-2 at [jm], j-1 at [jm^1])
    const v2f ssY = emag_ss(KY[jm], KY[jm ^ 1], Cy);
    const v2f ssP = emag_ss(KP[jm], KP[jm ^ 1], Cp);
    v2f d;
    d.x = 0.5f * (__builtin_amdgcn_sqrtf(ssY.x) - __builtin_amdgcn_sqrtf(ssP.x));
    d.y = 0.5f * (__builtin_amdgcn_sqrtf(ssY.y) - __builtin_amdgcn_sqrtf(ssP.y));
    d *= eg;
    accv = vfma(d, d, accv);

    // shift pipeline: slot jm (held plane j-2) now takes plane j
#pragma unroll
    for (int k = 0; k < 7; ++k) { KY[jm][k] = Cy[k]; KP[jm][k] = Cp[k]; }
  };

  // prologue: planes 0,1 -> pf[0]; planes 2,3 -> pf[1]   (48 loads in flight)
  asmLoad2(pf[0], z0 - 1);
  asmLoad2(pf[1], z0 + 1);

#pragma unroll 2
  for (int i = 0; i < NW; ++i) {                // 10 super-iters, planes 2i,2i+1
    v2f* q = pf[i % 2];
    // ONE wait per 2 planes: oldest 24 (this slot, issued 1 super-iter ago)
    // have landed; the other slot's 24 stay in flight.
    asm volatile("s_waitcnt vmcnt(24)"
                 : "+v"(q[0]),  "+v"(q[1]),  "+v"(q[2]),  "+v"(q[3]),
                   "+v"(q[4]),  "+v"(q[5]),  "+v"(q[6]),  "+v"(q[7]),
                   "+v"(q[8]),  "+v"(q[9]),  "+v"(q[10]), "+v"(q[11]),
                   "+v"(q[12]), "+v"(q[13]), "+v"(q[14]), "+v"(q[15]),
                   "+v"(q[16]), "+v"(q[17]), "+v"(q[18]), "+v"(q[19]),
                   "+v"(q[20]), "+v"(q[21]), "+v"(q[22]), "+v"(q[23]));
    __builtin_amdgcn_sched_barrier(0);

    consume(q,      0, 2 * i);                  // plane j=2i   (j%2 == 0)
    consume(q + 12, 1, 2 * i + 1);              // plane j=2i+1 (j%2 == 1)

    // slot consumed -> reissue with planes 2i+4, 2i+5 (z-clamped; WAR deps
    // order this after the ch-sum reads; 48 outstanding again after issue)
    asmLoad2(q, z0 + 3 + 2 * i);
  }

  // drain remaining in-flight loads before reduction / endpgm
  asm volatile("s_waitcnt vmcnt(0)");

  // ---- block reduction (only sync in the kernel) ----
  __shared__ float red[4];
  float acc = accv.x + accv.y;
#pragma unroll
  for (int off = 32; off > 0; off >>= 1) acc += __shfl_down(acc, off);
  if (lane == 0) red[ty] = acc;                 // wave id == ty (TX==64)
  __syncthreads();
  if (tid == 0) {
    const float s = (red[0] + red[1] + red[2] + red[3]) * INV_N;
    atomicAdd(out, s);
  }
}

}  // namespace

extern "C" void kernel_launch(void* const* d_in, const int* in_sizes, int n_in,
                              void* d_out, int out_size, void* d_ws, size_t ws_size,
                              hipStream_t stream) {
  const float* y  = (const float*)d_in[0];
  const float* yp = (const float*)d_in[1];
  float* out = (float*)d_out;

  // d_out is poisoned before every launch: zero via memset node (graph-capturable)
  hipMemsetAsync(out, 0, sizeof(float), stream);

  dim3 block(TX, TY, 1);                        // 256 threads = 4 full-row waves
  dim3 grid(YDIM / TY,                          // 32 y-tiles
            ZDIM / ZC,                          // 8 z-chunks
            2);                                 // batch  => 512 blocks, 2/CU
  gme_loss_kernel<<<grid, block, 0, stream>>>(y, yp, out);
}